// Round 5
// baseline (31742.038 us; speedup 1.0000x reference)
//
#include <hip/hip_runtime.h>
#include <hip/hip_bf16.h>

#define S_LEN 256
#define BATCH 64
#define EMB   300
#define EPAD  304
#define HID   512
#define G4H   2048
#define NCLS  25
#define TWOH  1024

using bf16 = __hip_bfloat16;
typedef _Float16 f16;
typedef f16 f16x2 __attribute__((ext_vector_type(2)));
typedef f16 f16x8 __attribute__((ext_vector_type(8)));
union V8 { f16x8 v; f16x2 p[4]; };

__device__ __forceinline__ float us2f(unsigned short u) {
    union { unsigned int i; float f; } v; v.i = ((unsigned int)u) << 16; return v.f;
}
__device__ __forceinline__ float sigm(float x) { return 1.f / (1.f + __expf(-x)); }

__device__ __forceinline__ float dot2f(f16x2 a, f16x2 b, float c) {
#if __has_builtin(__builtin_amdgcn_fdot2)
    return __builtin_amdgcn_fdot2(a, b, c, false);
#else
    return fmaf((float)a[1], (float)b[1], fmaf((float)a[0], (float)b[0], c));
#endif
}

// ---------------- embedding gather: x[t][b][e] (bf16, padded to EPAD) ----------------
__global__ void embed_kernel(const int* __restrict__ ids,
                             const float* __restrict__ emb,
                             bf16* __restrict__ x)
{
    int r = blockIdx.x;            // r = t*BATCH + b
    int t = r >> 6, b = r & 63;
    int id = ids[b * S_LEN + t];
    const float* src = emb + (size_t)id * EMB;
    bf16* dst = x + (size_t)r * EPAD;
    for (int e = threadIdx.x; e < EPAD; e += blockDim.x) {
        float v = (e < EMB) ? src[e] : 0.f;
        dst[e] = __float2bfloat16(v);
    }
}

// ------- transpose recurrent weights to f16: whT16[wl][u][g][k] = W[D+k][g*512+u] -------
__global__ void wtrans_kernel(const float* __restrict__ w_fw0, const float* __restrict__ w_bw0,
                              const float* __restrict__ w_fw1, const float* __restrict__ w_bw1,
                              f16* __restrict__ whT16)
{
    __shared__ float tile[32][33];
    int wl = blockIdx.z;
    const float* W; int D;
    if (wl == 0)      { W = w_fw0; D = EMB; }
    else if (wl == 1) { W = w_bw0; D = EMB; }
    else if (wl == 2) { W = w_fw1; D = TWOH; }
    else              { W = w_bw1; D = TWOH; }
    int k0 = blockIdx.x * 32, n0 = blockIdx.y * 32;
    int tx = threadIdx.x, ty = threadIdx.y;
    tile[ty][tx] = W[(size_t)(D + k0 + ty) * G4H + n0 + tx];
    __syncthreads();
    int k = k0 + tx;
    int n = n0 + ty;                  // gate-major column index
    int u = n & 511, g = n >> 9;
    whT16[(((size_t)wl * 512 + u) * 4 + g) * 512 + k] = (f16)tile[tx][ty];
}

// ---------------- input-gate precompute GEMM: G[z][t][b][4H] = gather(A) @ Wx + bias ----------------
__global__ __launch_bounds__(256)
void gates_gemm(const bf16* __restrict__ A, int strideA, int Keff,
                const float* __restrict__ W_fw, const float* __restrict__ W_bw,
                const float* __restrict__ b_fw, const float* __restrict__ b_bw,
                const int* __restrict__ lengths,
                bf16* __restrict__ G)
{
    const int z = blockIdx.z;
    const float* W    = z ? W_bw : W_fw;
    const float* bias = z ? b_bw : b_fw;
    const int m0 = blockIdx.x * 128;
    const int n0 = blockIdx.y * 128;
    const int tid = threadIdx.x;

    __shared__ __align__(16) float As[16][132];
    __shared__ __align__(16) float Bs[16][132];

    const int row_l = tid >> 1;
    const int kseg  = (tid & 1) * 8;
    int r = m0 + row_l;
    int t = r >> 6, b = r & 63;
    int st = t;
    if (z) { int len = lengths[b]; st = (t < len) ? (len - 1 - t) : t; }
    const bf16* arow = A + (size_t)(st * BATCH + b) * strideA + kseg;

    const int krow = tid >> 4;
    const int nseg = (tid & 15) * 8;
    const float* brow = W + (size_t)krow * G4H + n0 + nseg;

    const int ty = tid >> 4, tx = tid & 15;
    const int mt = ty * 8, nt = tx * 8;

    float acc[8][8];
#pragma unroll
    for (int i = 0; i < 8; ++i)
#pragma unroll
        for (int j = 0; j < 8; ++j) acc[i][j] = 0.f;

    for (int kt = 0; kt < Keff; kt += 16) {
        uint4 av = *reinterpret_cast<const uint4*>(arow + kt);
        const unsigned short* as8 = reinterpret_cast<const unsigned short*>(&av);
        float4 bld0 = *reinterpret_cast<const float4*>(brow + (size_t)kt * G4H);
        float4 bld1 = *reinterpret_cast<const float4*>(brow + (size_t)kt * G4H + 4);
#pragma unroll
        for (int j = 0; j < 8; ++j) As[kseg + j][row_l] = us2f(as8[j]);
        *reinterpret_cast<float4*>(&Bs[krow][nseg])     = bld0;
        *reinterpret_cast<float4*>(&Bs[krow][nseg + 4]) = bld1;
        __syncthreads();
#pragma unroll
        for (int k = 0; k < 16; ++k) {
            float4 a0 = *reinterpret_cast<const float4*>(&As[k][mt]);
            float4 a1 = *reinterpret_cast<const float4*>(&As[k][mt + 4]);
            float4 c0 = *reinterpret_cast<const float4*>(&Bs[k][nt]);
            float4 c1 = *reinterpret_cast<const float4*>(&Bs[k][nt + 4]);
            float a8[8] = {a0.x,a0.y,a0.z,a0.w,a1.x,a1.y,a1.z,a1.w};
            float b8[8] = {c0.x,c0.y,c0.z,c0.w,c1.x,c1.y,c1.z,c1.w};
#pragma unroll
            for (int i = 0; i < 8; ++i)
#pragma unroll
                for (int j = 0; j < 8; ++j)
                    acc[i][j] = fmaf(a8[i], b8[j], acc[i][j]);
        }
        __syncthreads();
    }

    float bv[8];
#pragma unroll
    for (int j = 0; j < 8; ++j) bv[j] = bias[n0 + nt + j];
#pragma unroll
    for (int i = 0; i < 8; ++i) {
        int rr = m0 + mt + i;
        bf16* gout = G + ((size_t)z * S_LEN * BATCH + rr) * G4H + n0 + nt;
        __align__(16) bf16 tmp[8];
#pragma unroll
        for (int j = 0; j < 8; ++j) tmp[j] = __float2bfloat16(acc[i][j] + bv[j]);
        *reinterpret_cast<uint4*>(gout) = *reinterpret_cast<const uint4*>(tmp);
    }
}

// ---------------- persistent LSTM recurrence (one layer, both dirs) ----------------
// grid 256 = 2 dirs x 8 b-tiles x 16 u-tiles. Block: 256 threads = 8 batches x 32 units.
// Weights (32u x 4g x 512k, f16) in LDS for all 256 steps. h exchange: f16 through MALL
// via relaxed agent atomics. Barrier: per-(dir,b-tile) GROUP of 16 blocks, one cumulative
// atomic counter (dependency-localized — no grid-wide sync needed).
__global__ __launch_bounds__(256, 1)
void lstm_seq(const bf16* __restrict__ G, const f16* __restrict__ whT16,
              const int* __restrict__ lengths, f16* __restrict__ hbuf,
              unsigned int* __restrict__ ctr, bf16* __restrict__ hcat)
{
    __shared__ __align__(16) f16 wlds[32 * 2056];   // row u: [g0 512][g1 512][g2 512][g3 512][pad 8]
    __shared__ __align__(16) f16 hl[8 * 520];       // row b: 512 + pad 8

    const int bx  = blockIdx.x;
    const int d   = bx >> 7;
    const int bt  = (bx >> 4) & 7;
    const int ut  = bx & 15;
    const int U0  = ut * 32;
    const int tid = threadIdx.x;
    const int b   = tid & 7;          // local batch
    const int ul  = tid >> 3;         // local unit 0..31
    const int bglob = bt * 8 + b;
    const int u     = U0 + ul;

    // one-time weight stage: 128 KB contiguous, coalesced
    {
        const f16* wsrc = whT16 + ((size_t)d * 512 + U0) * 2048;
#pragma unroll 4
        for (int i = 0; i < 32; ++i) {
            int c = tid + i * 256;                 // 16B chunk id, 0..8191
            int u2 = c >> 8, off = (c & 255) * 8;
            *reinterpret_cast<f16x8*>(&wlds[u2 * 2056 + off]) =
                *reinterpret_cast<const f16x8*>(wsrc + (size_t)c * 8);
        }
    }

    const int len = lengths[bglob];
    float c_reg = 0.f, hown = 0.f;
    unsigned int* ctrp = ctr + (d * 8 + bt) * 32;   // 128B-spaced group counters

    for (int t = 0; t < S_LEN; ++t) {
        // ---- issue h (agent-coherent, 4 x 8B = full 8x512 chunk) + G loads ----
        const unsigned long long* hsrc = (const unsigned long long*)
            (hbuf + (size_t)(((t & 1) * 2 + d) * BATCH + bt * 8) * HID);
        unsigned long long pv[4];
#pragma unroll
        for (int i = 0; i < 4; ++i)
            pv[i] = __hip_atomic_load(hsrc + tid + i * 256,
                                      __ATOMIC_RELAXED, __HIP_MEMORY_SCOPE_AGENT);
        const bf16* gp = G + ((size_t)(d * S_LEN + t) * BATCH + bglob) * G4H + U0 + ul;
        float g0 = __bfloat162float(gp[0]);
        float g1 = __bfloat162float(gp[512]);
        float g2 = __bfloat162float(gp[1024]);
        float g3 = __bfloat162float(gp[1536]);

        // ---- stage h into LDS (hl free: previous step's compute done pre-barrier) ----
#pragma unroll
        for (int i = 0; i < 4; ++i) {
            int f = (tid + i * 256) * 4;           // f16 flat index 0..4092
            *reinterpret_cast<unsigned long long*>(&hl[(f >> 9) * 520 + (f & 511)]) = pv[i];
        }
        __syncthreads();

        // ---- 512-k dot products, 4 gates, dual accumulator chains ----
        float a00 = g0, a01 = 0.f, a10 = g1, a11 = 0.f;
        float a20 = g2, a21 = 0.f, a30 = g3, a31 = 0.f;
        const f16* wb = wlds + (size_t)ul * 2056;
        const f16* hb = hl + (size_t)b * 520;
#pragma unroll
        for (int kb = 0; kb < 512; kb += 16) {
            V8 h0, h1, w;
            h0.v = *reinterpret_cast<const f16x8*>(hb + kb);
            h1.v = *reinterpret_cast<const f16x8*>(hb + kb + 8);
            w.v = *reinterpret_cast<const f16x8*>(wb + kb);
            a00 = dot2f(w.p[0], h0.p[0], a00); a00 = dot2f(w.p[1], h0.p[1], a00);
            a00 = dot2f(w.p[2], h0.p[2], a00); a00 = dot2f(w.p[3], h0.p[3], a00);
            w.v = *reinterpret_cast<const f16x8*>(wb + kb + 8);
            a01 = dot2f(w.p[0], h1.p[0], a01); a01 = dot2f(w.p[1], h1.p[1], a01);
            a01 = dot2f(w.p[2], h1.p[2], a01); a01 = dot2f(w.p[3], h1.p[3], a01);
            w.v = *reinterpret_cast<const f16x8*>(wb + 512 + kb);
            a10 = dot2f(w.p[0], h0.p[0], a10); a10 = dot2f(w.p[1], h0.p[1], a10);
            a10 = dot2f(w.p[2], h0.p[2], a10); a10 = dot2f(w.p[3], h0.p[3], a10);
            w.v = *reinterpret_cast<const f16x8*>(wb + 512 + kb + 8);
            a11 = dot2f(w.p[0], h1.p[0], a11); a11 = dot2f(w.p[1], h1.p[1], a11);
            a11 = dot2f(w.p[2], h1.p[2], a11); a11 = dot2f(w.p[3], h1.p[3], a11);
            w.v = *reinterpret_cast<const f16x8*>(wb + 1024 + kb);
            a20 = dot2f(w.p[0], h0.p[0], a20); a20 = dot2f(w.p[1], h0.p[1], a20);
            a20 = dot2f(w.p[2], h0.p[2], a20); a20 = dot2f(w.p[3], h0.p[3], a20);
            w.v = *reinterpret_cast<const f16x8*>(wb + 1024 + kb + 8);
            a21 = dot2f(w.p[0], h1.p[0], a21); a21 = dot2f(w.p[1], h1.p[1], a21);
            a21 = dot2f(w.p[2], h1.p[2], a21); a21 = dot2f(w.p[3], h1.p[3], a21);
            w.v = *reinterpret_cast<const f16x8*>(wb + 1536 + kb);
            a30 = dot2f(w.p[0], h0.p[0], a30); a30 = dot2f(w.p[1], h0.p[1], a30);
            a30 = dot2f(w.p[2], h0.p[2], a30); a30 = dot2f(w.p[3], h0.p[3], a30);
            w.v = *reinterpret_cast<const f16x8*>(wb + 1536 + kb + 8);
            a31 = dot2f(w.p[0], h1.p[0], a31); a31 = dot2f(w.p[1], h1.p[1], a31);
            a31 = dot2f(w.p[2], h1.p[2], a31); a31 = dot2f(w.p[3], h1.p[3], a31);
        }

        // ---- activation + state ----
        bool msk = (t < len);
        float i_ = sigm(a00 + a01);
        float j_ = tanhf(a10 + a11);
        float f_ = sigm(a20 + a21 + 1.0f);          // FORGET_BIAS
        float o_ = sigm(a30 + a31);
        float cn = f_ * c_reg + i_ * j_;
        float hn = o_ * tanhf(cn);
        if (msk) c_reg = cn;
        hown = msk ? hn : hown;

        // ---- publish h (f16, write-through agent) + hcat (plain) ----
        union { f16 h; unsigned short s; } cv; cv.h = (f16)hown;
        __hip_atomic_store((unsigned short*)(hbuf +
            (size_t)((((t + 1) & 1) * 2 + d) * BATCH + bglob) * HID + u),
            cv.s, __ATOMIC_RELAXED, __HIP_MEMORY_SCOPE_AGENT);
        int p = (d == 1 && msk) ? (len - 1 - t) : t;
        hcat[((size_t)p * BATCH + bglob) * TWOH + (size_t)d * HID + u] =
            __float2bfloat16(msk ? hn : 0.f);

        // ---- group barrier: 16 blocks of (d, bt), one cumulative counter ----
        asm volatile("s_waitcnt vmcnt(0)" ::: "memory");
        __syncthreads();
        if (tid == 0) {
            __hip_atomic_fetch_add(ctrp, 1u, __ATOMIC_RELAXED, __HIP_MEMORY_SCOPE_AGENT);
            unsigned tgt = 16u * (unsigned)(t + 1);
            while (__hip_atomic_load(ctrp, __ATOMIC_RELAXED, __HIP_MEMORY_SCOPE_AGENT) < tgt)
                __builtin_amdgcn_s_sleep(1);
        }
        __syncthreads();
    }
}

// ---------------- dense + softmax: out[b][s][c] ----------------
__global__ __launch_bounds__(256)
void dense_softmax(const bf16* __restrict__ h, const float* __restrict__ wd,
                   const float* __restrict__ bd, float* __restrict__ out)
{
    __shared__ __align__(16) bf16 wdT[NCLS][1032];
    for (int i = threadIdx.x; i < TWOH * NCLS; i += 256) {
        int k = i / NCLS, c = i % NCLS;    // wd[k][c]
        wdT[c][k] = __float2bfloat16(wd[i]);
    }
    __syncthreads();
    const int c  = threadIdx.x & 31;
    const int rl = threadIdx.x >> 5;
#pragma unroll 1
    for (int pass = 0; pass < 8; ++pass) {
        int r = blockIdx.x * 64 + pass * 8 + rl;   // r = s*BATCH + b
        const bf16* hrow = h + (size_t)r * TWOH;
        float acc = -1e30f;
        if (c < NCLS) {
            acc = 0.f;
            for (int k = 0; k < TWOH; k += 8) {
                uint4 hv = *reinterpret_cast<const uint4*>(hrow + k);
                uint4 wv = *reinterpret_cast<const uint4*>(&wdT[c][k]);
                const unsigned short* hs  = reinterpret_cast<const unsigned short*>(&hv);
                const unsigned short* wsp = reinterpret_cast<const unsigned short*>(&wv);
#pragma unroll
                for (int j = 0; j < 8; ++j) acc += us2f(hs[j]) * us2f(wsp[j]);
            }
            acc += bd[c];
        }
        float mx = acc;
#pragma unroll
        for (int o = 16; o; o >>= 1) mx = fmaxf(mx, __shfl_xor(mx, o, 32));
        float e = (c < NCLS) ? __expf(acc - mx) : 0.f;
        float sm = e;
#pragma unroll
        for (int o = 16; o; o >>= 1) sm += __shfl_xor(sm, o, 32);
        if (c < NCLS) {
            int s = r >> 6, b = r & 63;
            out[((size_t)b * S_LEN + s) * NCLS + c] = e / sm;
        }
    }
}

extern "C" void kernel_launch(void* const* d_in, const int* in_sizes, int n_in,
                              void* d_out, int out_size, void* d_ws, size_t ws_size,
                              hipStream_t stream)
{
    const int*   ids   = (const int*)  d_in[0];
    const int*   lens  = (const int*)  d_in[1];
    const float* emb   = (const float*)d_in[2];
    const float* w_fw0 = (const float*)d_in[3];
    const float* b_fw0 = (const float*)d_in[4];
    const float* w_bw0 = (const float*)d_in[5];
    const float* b_bw0 = (const float*)d_in[6];
    const float* w_fw1 = (const float*)d_in[7];
    const float* b_fw1 = (const float*)d_in[8];
    const float* w_bw1 = (const float*)d_in[9];
    const float* b_bw1 = (const float*)d_in[10];
    const float* wd    = (const float*)d_in[11];
    const float* bd    = (const float*)d_in[12];
    float* out = (float*)d_out;

    char* ws = (char*)d_ws;
    size_t off = 0;
    auto alloc = [&](size_t bytes) {
        void* p = ws + off;
        off += (bytes + 255) & ~(size_t)255;
        return p;
    };
    bf16*  x      = (bf16*) alloc((size_t)S_LEN * BATCH * EPAD * 2);
    bf16*  G      = (bf16*) alloc((size_t)2 * S_LEN * BATCH * G4H * 2);
    bf16*  hcat0  = (bf16*) alloc((size_t)S_LEN * BATCH * TWOH * 2);
    bf16*  hcat1  = (bf16*) alloc((size_t)S_LEN * BATCH * TWOH * 2);
    f16*   whT16  = (f16*)  alloc((size_t)4 * 512 * 4 * 512 * 2);
    f16*   hbuf   = (f16*)  alloc((size_t)2 * 2 * BATCH * HID * 2);
    unsigned int* ctr = (unsigned int*)alloc((size_t)16 * 32 * 4);

    embed_kernel<<<S_LEN * BATCH, 128, 0, stream>>>(ids, emb, x);
    wtrans_kernel<<<dim3(16, 64, 4), dim3(32, 32), 0, stream>>>(w_fw0, w_bw0, w_fw1, w_bw1, whT16);

    for (int layer = 0; layer < 2; ++layer) {
        hipMemsetAsync(hbuf, 0, (size_t)2 * 2 * BATCH * HID * 2, stream);
        hipMemsetAsync(ctr, 0, (size_t)16 * 32 * 4, stream);
        const bf16* Ain   = layer ? hcat0 : x;
        int strideA       = layer ? TWOH : EPAD;
        const float* Wf   = layer ? w_fw1 : w_fw0;
        const float* Wb   = layer ? w_bw1 : w_bw0;
        const float* bfp  = layer ? b_fw1 : b_fw0;
        const float* bbp  = layer ? b_bw1 : b_bw0;
        bf16* hcat        = layer ? hcat1 : hcat0;

        gates_gemm<<<dim3(128, 16, 2), 256, 0, stream>>>(Ain, strideA, strideA,
                                                         Wf, Wb, bfp, bbp, lens, G);

        const bf16*  Gp   = G;
        const f16*   whp  = whT16 + (size_t)layer * 2 * 512 * 2048;
        const int*   lnp  = lens;
        f16*         hbp  = hbuf;
        unsigned int* ctp = ctr;
        bf16*        hcp  = hcat;
        void* args[6] = { &Gp, &whp, &lnp, &hbp, &ctp, &hcp };
        hipLaunchCooperativeKernel(lstm_seq, dim3(256), dim3(256), args, 0, stream);
    }
    dense_softmax<<<256, 256, 0, stream>>>(hcat1, wd, bd, out);

    (void)in_sizes; (void)n_in; (void)out_size; (void)ws_size;
}

// Round 6
// 7611.240 us; speedup vs baseline: 4.1704x; 4.1704x over previous
//
#include <hip/hip_runtime.h>
#include <hip/hip_bf16.h>

#define S_LEN 256
#define BATCH 64
#define EMB   300
#define EPAD  304
#define HID   512
#define G4H   2048
#define NCLS  25
#define TWOH  1024

using bf16 = __hip_bfloat16;
typedef _Float16 f16;
typedef f16 f16x2 __attribute__((ext_vector_type(2)));
typedef f16 f16x4 __attribute__((ext_vector_type(4)));
typedef f16 f16x8 __attribute__((ext_vector_type(8)));
union V8 { f16x8 v; f16x2 p[4]; };

__device__ __forceinline__ float us2f(unsigned short u) {
    union { unsigned int i; float f; } v; v.i = ((unsigned int)u) << 16; return v.f;
}
__device__ __forceinline__ float sigm(float x) { return 1.f / (1.f + __expf(-x)); }

__device__ __forceinline__ float dot2f(f16x2 a, f16x2 b, float c) {
#if __has_builtin(__builtin_amdgcn_fdot2)
    return __builtin_amdgcn_fdot2(a, b, c, false);
#else
    return fmaf((float)a[1], (float)b[1], fmaf((float)a[0], (float)b[0], c));
#endif
}

// ---------------- embedding gather: x[t][b][e] (bf16, padded to EPAD) ----------------
__global__ void embed_kernel(const int* __restrict__ ids,
                             const float* __restrict__ emb,
                             bf16* __restrict__ x)
{
    int r = blockIdx.x;            // r = t*BATCH + b
    int t = r >> 6, b = r & 63;
    int id = ids[b * S_LEN + t];
    const float* src = emb + (size_t)id * EMB;
    bf16* dst = x + (size_t)r * EPAD;
    for (int e = threadIdx.x; e < EPAD; e += blockDim.x) {
        float v = (e < EMB) ? src[e] : 0.f;
        dst[e] = __float2bfloat16(v);
    }
}

// ------- transpose recurrent weights to f16: whT16[wl][u][g][k] = W[D+k][g*512+u] -------
__global__ void wtrans_kernel(const float* __restrict__ w_fw0, const float* __restrict__ w_bw0,
                              const float* __restrict__ w_fw1, const float* __restrict__ w_bw1,
                              f16* __restrict__ whT16)
{
    __shared__ float tile[32][33];
    int wl = blockIdx.z;
    const float* W; int D;
    if (wl == 0)      { W = w_fw0; D = EMB; }
    else if (wl == 1) { W = w_bw0; D = EMB; }
    else if (wl == 2) { W = w_fw1; D = TWOH; }
    else              { W = w_bw1; D = TWOH; }
    int k0 = blockIdx.x * 32, n0 = blockIdx.y * 32;
    int tx = threadIdx.x, ty = threadIdx.y;
    tile[ty][tx] = W[(size_t)(D + k0 + ty) * G4H + n0 + tx];
    __syncthreads();
    int k = k0 + tx;
    int n = n0 + ty;                  // gate-major column index
    int u = n & 511, g = n >> 9;
    whT16[(((size_t)wl * 512 + u) * 4 + g) * 512 + k] = (f16)tile[tx][ty];
}

// ---------------- input-gate precompute GEMM: G[z][t][b][4H] = gather(A) @ Wx + bias ----------------
__global__ __launch_bounds__(256)
void gates_gemm(const bf16* __restrict__ A, int strideA, int Keff,
                const float* __restrict__ W_fw, const float* __restrict__ W_bw,
                const float* __restrict__ b_fw, const float* __restrict__ b_bw,
                const int* __restrict__ lengths,
                bf16* __restrict__ G)
{
    const int z = blockIdx.z;
    const float* W    = z ? W_bw : W_fw;
    const float* bias = z ? b_bw : b_fw;
    const int m0 = blockIdx.x * 128;
    const int n0 = blockIdx.y * 128;
    const int tid = threadIdx.x;

    __shared__ __align__(16) float As[16][132];
    __shared__ __align__(16) float Bs[16][132];

    const int row_l = tid >> 1;
    const int kseg  = (tid & 1) * 8;
    int r = m0 + row_l;
    int t = r >> 6, b = r & 63;
    int st = t;
    if (z) { int len = lengths[b]; st = (t < len) ? (len - 1 - t) : t; }
    const bf16* arow = A + (size_t)(st * BATCH + b) * strideA + kseg;

    const int krow = tid >> 4;
    const int nseg = (tid & 15) * 8;
    const float* brow = W + (size_t)krow * G4H + n0 + nseg;

    const int ty = tid >> 4, tx = tid & 15;
    const int mt = ty * 8, nt = tx * 8;

    float acc[8][8];
#pragma unroll
    for (int i = 0; i < 8; ++i)
#pragma unroll
        for (int j = 0; j < 8; ++j) acc[i][j] = 0.f;

    for (int kt = 0; kt < Keff; kt += 16) {
        uint4 av = *reinterpret_cast<const uint4*>(arow + kt);
        const unsigned short* as8 = reinterpret_cast<const unsigned short*>(&av);
        float4 bld0 = *reinterpret_cast<const float4*>(brow + (size_t)kt * G4H);
        float4 bld1 = *reinterpret_cast<const float4*>(brow + (size_t)kt * G4H + 4);
#pragma unroll
        for (int j = 0; j < 8; ++j) As[kseg + j][row_l] = us2f(as8[j]);
        *reinterpret_cast<float4*>(&Bs[krow][nseg])     = bld0;
        *reinterpret_cast<float4*>(&Bs[krow][nseg + 4]) = bld1;
        __syncthreads();
#pragma unroll
        for (int k = 0; k < 16; ++k) {
            float4 a0 = *reinterpret_cast<const float4*>(&As[k][mt]);
            float4 a1 = *reinterpret_cast<const float4*>(&As[k][mt + 4]);
            float4 c0 = *reinterpret_cast<const float4*>(&Bs[k][nt]);
            float4 c1 = *reinterpret_cast<const float4*>(&Bs[k][nt + 4]);
            float a8[8] = {a0.x,a0.y,a0.z,a0.w,a1.x,a1.y,a1.z,a1.w};
            float b8[8] = {c0.x,c0.y,c0.z,c0.w,c1.x,c1.y,c1.z,c1.w};
#pragma unroll
            for (int i = 0; i < 8; ++i)
#pragma unroll
                for (int j = 0; j < 8; ++j)
                    acc[i][j] = fmaf(a8[i], b8[j], acc[i][j]);
        }
        __syncthreads();
    }

    float bv[8];
#pragma unroll
    for (int j = 0; j < 8; ++j) bv[j] = bias[n0 + nt + j];
#pragma unroll
    for (int i = 0; i < 8; ++i) {
        int rr = m0 + mt + i;
        bf16* gout = G + ((size_t)z * S_LEN * BATCH + rr) * G4H + n0 + nt;
        __align__(16) bf16 tmp[8];
#pragma unroll
        for (int j = 0; j < 8; ++j) tmp[j] = __float2bfloat16(acc[i][j] + bv[j]);
        *reinterpret_cast<uint4*>(gout) = *reinterpret_cast<const uint4*>(tmp);
    }
}

// ---------------- persistent LSTM recurrence (one layer, both dirs) ----------------
// R3 skeleton: grid 256 = 2 dirs x 128 u-tiles (4 units). Block 256 thr = 64 b x 4 uu.
// Upgrades: f16 weights in LDS (16.6KB) + fdot2; h staged to LDS as f16; per-direction
// flag barrier (store-once flags, read-only polling — NO contended RMW, that was R5's
// 55GB/dispatch disaster); split-phase signal-early/wait-late hides hcat+G-prefetch.
__global__ __launch_bounds__(256, 1)
void lstm_seq(const bf16* __restrict__ G, const f16* __restrict__ whT16,
              const int* __restrict__ lengths, float* __restrict__ hbuf,
              unsigned int* __restrict__ flags, bf16* __restrict__ hcat)
{
    __shared__ __align__(16) f16 wlds[16 * 520];   // row r=uu*4+g: 512 k + pad 8
    __shared__ __align__(16) f16 hl[64 * 72];      // 64-k chunk: row b: 64 + pad 8

    const int bx   = blockIdx.x;
    const int d    = bx >> 7;
    const int ublk = bx & 127;
    const int u0   = ublk * 4;
    const int tid  = threadIdx.x;
    const int b    = tid >> 2, uu = tid & 3;
    const int u    = u0 + uu;

    // one-time weight stage: 16 rows (u-major, g-minor) x 512 f16 = 16KB contiguous
    {
        const f16* wsrc = whT16 + ((size_t)(d * 512 + u0) * 4) * 512;
#pragma unroll
        for (int i = 0; i < 8; ++i) {
            int c = tid + i * 256;                 // 8B chunk id 0..2047
            int r = c >> 7, off = (c & 127) * 4;
            *reinterpret_cast<f16x4*>(&wlds[r * 520 + off]) =
                *reinterpret_cast<const f16x4*>(wsrc + (size_t)c * 4);
        }
    }

    const int len = lengths[b];
    float c_reg = 0.f, hown = 0.f;

    // staging geometry: element e = i*256+tid of a 64b x 64k chunk
    int sbb[16], skq[16];
#pragma unroll
    for (int i = 0; i < 16; ++i) {
        int e = i * 256 + tid;
        sbb[i] = e >> 6; skq[i] = e & 63;
    }

    const f16* w0 = wlds + (uu * 4 + 0) * 520;
    const f16* w1 = wlds + (uu * 4 + 1) * 520;
    const f16* w2 = wlds + (uu * 4 + 2) * 520;
    const f16* w3 = wlds + (uu * 4 + 3) * 520;
    const f16* hb = hl + b * 72;

    // G for t=0
    const bf16* gp0 = G + ((size_t)(d * S_LEN + 0) * BATCH + b) * G4H + u;
    float g0 = __bfloat162float(gp0[0]);
    float g1 = __bfloat162float(gp0[512]);
    float g2 = __bfloat162float(gp0[1024]);
    float g3 = __bfloat162float(gp0[1536]);

    for (int t = 0; t < S_LEN; ++t) {
        const float* hsrc = hbuf + (size_t)((t & 1) * 2 + d) * BATCH * HID;

        float pf[16];
#pragma unroll
        for (int i = 0; i < 16; ++i)     // prefetch chunk 0 (agent-coherent)
            pf[i] = __hip_atomic_load(hsrc + (size_t)sbb[i] * HID + skq[i],
                                      __ATOMIC_RELAXED, __HIP_MEMORY_SCOPE_AGENT);

        float a00 = g0, a01 = 0.f, a10 = g1, a11 = 0.f;
        float a20 = g2, a21 = 0.f, a30 = g3, a31 = 0.f;

        for (int kc = 0; kc < HID; kc += 64) {
            __syncthreads();                    // prior chunk's reads done
#pragma unroll
            for (int i = 0; i < 16; ++i) hl[sbb[i] * 72 + skq[i]] = (f16)pf[i];
            __syncthreads();
            if (kc + 64 < HID) {
#pragma unroll
                for (int i = 0; i < 16; ++i)
                    pf[i] = __hip_atomic_load(hsrc + (size_t)sbb[i] * HID + kc + 64 + skq[i],
                                              __ATOMIC_RELAXED, __HIP_MEMORY_SCOPE_AGENT);
            }
#pragma unroll
            for (int kb = 0; kb < 64; kb += 16) {
                V8 h0, h1, w;
                h0.v = *reinterpret_cast<const f16x8*>(hb + kb);
                h1.v = *reinterpret_cast<const f16x8*>(hb + kb + 8);
                w.v = *reinterpret_cast<const f16x8*>(w0 + kc + kb);
                a00 = dot2f(w.p[0], h0.p[0], a00); a00 = dot2f(w.p[1], h0.p[1], a00);
                a00 = dot2f(w.p[2], h0.p[2], a00); a00 = dot2f(w.p[3], h0.p[3], a00);
                w.v = *reinterpret_cast<const f16x8*>(w0 + kc + kb + 8);
                a01 = dot2f(w.p[0], h1.p[0], a01); a01 = dot2f(w.p[1], h1.p[1], a01);
                a01 = dot2f(w.p[2], h1.p[2], a01); a01 = dot2f(w.p[3], h1.p[3], a01);
                w.v = *reinterpret_cast<const f16x8*>(w1 + kc + kb);
                a10 = dot2f(w.p[0], h0.p[0], a10); a10 = dot2f(w.p[1], h0.p[1], a10);
                a10 = dot2f(w.p[2], h0.p[2], a10); a10 = dot2f(w.p[3], h0.p[3], a10);
                w.v = *reinterpret_cast<const f16x8*>(w1 + kc + kb + 8);
                a11 = dot2f(w.p[0], h1.p[0], a11); a11 = dot2f(w.p[1], h1.p[1], a11);
                a11 = dot2f(w.p[2], h1.p[2], a11); a11 = dot2f(w.p[3], h1.p[3], a11);
                w.v = *reinterpret_cast<const f16x8*>(w2 + kc + kb);
                a20 = dot2f(w.p[0], h0.p[0], a20); a20 = dot2f(w.p[1], h0.p[1], a20);
                a20 = dot2f(w.p[2], h0.p[2], a20); a20 = dot2f(w.p[3], h0.p[3], a20);
                w.v = *reinterpret_cast<const f16x8*>(w2 + kc + kb + 8);
                a21 = dot2f(w.p[0], h1.p[0], a21); a21 = dot2f(w.p[1], h1.p[1], a21);
                a21 = dot2f(w.p[2], h1.p[2], a21); a21 = dot2f(w.p[3], h1.p[3], a21);
                w.v = *reinterpret_cast<const f16x8*>(w3 + kc + kb);
                a30 = dot2f(w.p[0], h0.p[0], a30); a30 = dot2f(w.p[1], h0.p[1], a30);
                a30 = dot2f(w.p[2], h0.p[2], a30); a30 = dot2f(w.p[3], h0.p[3], a30);
                w.v = *reinterpret_cast<const f16x8*>(w3 + kc + kb + 8);
                a31 = dot2f(w.p[0], h1.p[0], a31); a31 = dot2f(w.p[1], h1.p[1], a31);
                a31 = dot2f(w.p[2], h1.p[2], a31); a31 = dot2f(w.p[3], h1.p[3], a31);
            }
        }

        // ---- activation + state ----
        bool msk = (t < len);
        float i_ = sigm(a00 + a01);
        float j_ = tanhf(a10 + a11);
        float f_ = sigm(a20 + a21 + 1.0f);          // FORGET_BIAS
        float o_ = sigm(a30 + a31);
        float cn = f_ * c_reg + i_ * j_;
        float hn = o_ * tanhf(cn);
        if (msk) c_reg = cn;
        hown = msk ? hn : hown;

        // ---- publish h (f32, agent write-through) then SIGNAL EARLY ----
        __hip_atomic_store(&hbuf[((size_t)(((t + 1) & 1) * 2 + d) * BATCH + b) * HID + u],
                           hown, __ATOMIC_RELAXED, __HIP_MEMORY_SCOPE_AGENT);
        asm volatile("s_waitcnt vmcnt(0)" ::: "memory");  // h store at coherence point
        __syncthreads();                                   // all waves drained
        if (tid == 0)
            __hip_atomic_store(&flags[(size_t)t * 256 + d * 128 + ublk], 1u,
                               __ATOMIC_RELAXED, __HIP_MEMORY_SCOPE_AGENT);

        // ---- shadow work: hcat store + next-step G prefetch ----
        int p = (d == 1 && msk) ? (len - 1 - t) : t;
        hcat[((size_t)p * BATCH + b) * TWOH + (size_t)d * HID + u] =
            __float2bfloat16(msk ? hn : 0.f);
        int tn = (t + 1 < S_LEN) ? t + 1 : t;
        const bf16* gpn = G + ((size_t)(d * S_LEN + tn) * BATCH + b) * G4H + u;
        float n0 = __bfloat162float(gpn[0]);
        float n1 = __bfloat162float(gpn[512]);
        float n2 = __bfloat162float(gpn[1024]);
        float n3 = __bfloat162float(gpn[1536]);

        // ---- wait: poll this direction's 128 flags (read-only) ----
        if (tid < 64) {
            const unsigned int* fb = flags + (size_t)t * 256 + d * 128;
            while (true) {
                unsigned f0 = __hip_atomic_load(fb + tid,      __ATOMIC_RELAXED, __HIP_MEMORY_SCOPE_AGENT);
                unsigned f1 = __hip_atomic_load(fb + tid + 64, __ATOMIC_RELAXED, __HIP_MEMORY_SCOPE_AGENT);
                if (__all((f0 & f1) == 1u)) break;
                __builtin_amdgcn_s_sleep(2);
            }
        }
        __syncthreads();
        g0 = n0; g1 = n1; g2 = n2; g3 = n3;
    }
}

// ---------------- dense + softmax: out[b][s][c] ----------------
__global__ __launch_bounds__(256)
void dense_softmax(const bf16* __restrict__ h, const float* __restrict__ wd,
                   const float* __restrict__ bd, float* __restrict__ out)
{
    __shared__ __align__(16) bf16 wdT[NCLS][1032];
    for (int i = threadIdx.x; i < TWOH * NCLS; i += 256) {
        int k = i / NCLS, c = i % NCLS;    // wd[k][c]
        wdT[c][k] = __float2bfloat16(wd[i]);
    }
    __syncthreads();
    const int c  = threadIdx.x & 31;
    const int rl = threadIdx.x >> 5;
#pragma unroll 1
    for (int pass = 0; pass < 8; ++pass) {
        int r = blockIdx.x * 64 + pass * 8 + rl;   // r = s*BATCH + b
        const bf16* hrow = h + (size_t)r * TWOH;
        float acc = -1e30f;
        if (c < NCLS) {
            acc = 0.f;
            for (int k = 0; k < TWOH; k += 8) {
                uint4 hv = *reinterpret_cast<const uint4*>(hrow + k);
                uint4 wv = *reinterpret_cast<const uint4*>(&wdT[c][k]);
                const unsigned short* hs  = reinterpret_cast<const unsigned short*>(&hv);
                const unsigned short* wsp = reinterpret_cast<const unsigned short*>(&wv);
#pragma unroll
                for (int j = 0; j < 8; ++j) acc += us2f(hs[j]) * us2f(wsp[j]);
            }
            acc += bd[c];
        }
        float mx = acc;
#pragma unroll
        for (int o = 16; o; o >>= 1) mx = fmaxf(mx, __shfl_xor(mx, o, 32));
        float e = (c < NCLS) ? __expf(acc - mx) : 0.f;
        float sm = e;
#pragma unroll
        for (int o = 16; o; o >>= 1) sm += __shfl_xor(sm, o, 32);
        if (c < NCLS) {
            int s = r >> 6, b = r & 63;
            out[((size_t)b * S_LEN + s) * NCLS + c] = e / sm;
        }
    }
}

extern "C" void kernel_launch(void* const* d_in, const int* in_sizes, int n_in,
                              void* d_out, int out_size, void* d_ws, size_t ws_size,
                              hipStream_t stream)
{
    const int*   ids   = (const int*)  d_in[0];
    const int*   lens  = (const int*)  d_in[1];
    const float* emb   = (const float*)d_in[2];
    const float* w_fw0 = (const float*)d_in[3];
    const float* b_fw0 = (const float*)d_in[4];
    const float* w_bw0 = (const float*)d_in[5];
    const float* b_bw0 = (const float*)d_in[6];
    const float* w_fw1 = (const float*)d_in[7];
    const float* b_fw1 = (const float*)d_in[8];
    const float* w_bw1 = (const float*)d_in[9];
    const float* b_bw1 = (const float*)d_in[10];
    const float* wd    = (const float*)d_in[11];
    const float* bd    = (const float*)d_in[12];
    float* out = (float*)d_out;

    char* ws = (char*)d_ws;
    size_t off = 0;
    auto alloc = [&](size_t bytes) {
        void* p = ws + off;
        off += (bytes + 255) & ~(size_t)255;
        return p;
    };
    bf16*  x      = (bf16*) alloc((size_t)S_LEN * BATCH * EPAD * 2);
    bf16*  G      = (bf16*) alloc((size_t)2 * S_LEN * BATCH * G4H * 2);
    bf16*  hcat0  = (bf16*) alloc((size_t)S_LEN * BATCH * TWOH * 2);
    bf16*  hcat1  = (bf16*) alloc((size_t)S_LEN * BATCH * TWOH * 2);
    f16*   whT16  = (f16*)  alloc((size_t)4 * 512 * 4 * 512 * 2);
    float* hbuf   = (float*)alloc((size_t)2 * 2 * BATCH * HID * 4);
    unsigned int* flags = (unsigned int*)alloc((size_t)S_LEN * 256 * 4);

    embed_kernel<<<S_LEN * BATCH, 128, 0, stream>>>(ids, emb, x);
    wtrans_kernel<<<dim3(16, 64, 4), dim3(32, 32), 0, stream>>>(w_fw0, w_bw0, w_fw1, w_bw1, whT16);

    for (int layer = 0; layer < 2; ++layer) {
        hipMemsetAsync(hbuf, 0, (size_t)2 * 2 * BATCH * HID * 4, stream);
        hipMemsetAsync(flags, 0, (size_t)S_LEN * 256 * 4, stream);
        const bf16* Ain   = layer ? hcat0 : x;
        int strideA       = layer ? TWOH : EPAD;
        const float* Wf   = layer ? w_fw1 : w_fw0;
        const float* Wb   = layer ? w_bw1 : w_bw0;
        const float* bfp  = layer ? b_fw1 : b_fw0;
        const float* bbp  = layer ? b_bw1 : b_bw0;
        bf16* hcat        = layer ? hcat1 : hcat0;

        gates_gemm<<<dim3(128, 16, 2), 256, 0, stream>>>(Ain, strideA, strideA,
                                                         Wf, Wb, bfp, bbp, lens, G);

        const bf16*  Gp   = G;
        const f16*   whp  = whT16 + (size_t)layer * 2 * 512 * 2048;
        const int*   lnp  = lens;
        float*       hbp  = hbuf;
        unsigned int* flp = flags;
        bf16*        hcp  = hcat;
        void* args[6] = { &Gp, &whp, &lnp, &hbp, &flp, &hcp };
        hipLaunchCooperativeKernel(lstm_seq, dim3(256), dim3(256), args, 0, stream);
    }
    dense_softmax<<<256, 256, 0, stream>>>(hcat1, wd, bd, out);

    (void)in_sizes; (void)n_in; (void)out_size; (void)ws_size;
}

// Round 7
// 6695.005 us; speedup vs baseline: 4.7412x; 1.1369x over previous
//
#include <hip/hip_runtime.h>
#include <hip/hip_bf16.h>

#define S_LEN 256
#define BATCH 64
#define EMB   300
#define EPAD  304
#define HID   512
#define G4H   2048
#define NCLS  25
#define TWOH  1024

using bf16 = __hip_bfloat16;
typedef short bf8v __attribute__((ext_vector_type(8)));   // 8 bf16 in 4 VGPRs
typedef float f32x4 __attribute__((ext_vector_type(4)));
typedef unsigned long long ull;

__device__ __forceinline__ float us2f(unsigned short u) {
    union { unsigned int i; float f; } v; v.i = ((unsigned int)u) << 16; return v.f;
}
__device__ __forceinline__ float sigm(float x) { return 1.f / (1.f + __expf(-x)); }

// ---------------- embedding gather: x[t][b][e] (bf16, padded to EPAD) ----------------
__global__ void embed_kernel(const int* __restrict__ ids,
                             const float* __restrict__ emb,
                             bf16* __restrict__ x)
{
    int r = blockIdx.x;            // r = t*BATCH + b
    int t = r >> 6, b = r & 63;
    int id = ids[b * S_LEN + t];
    const float* src = emb + (size_t)id * EMB;
    bf16* dst = x + (size_t)r * EPAD;
    for (int e = threadIdx.x; e < EPAD; e += blockDim.x) {
        float v = (e < EMB) ? src[e] : 0.f;
        dst[e] = __float2bfloat16(v);
    }
}

// ------- transpose recurrent weights to bf16: whTb[wl][u][g][k] = W[D+k][g*512+u] -------
__global__ void wtrans_kernel(const float* __restrict__ w_fw0, const float* __restrict__ w_bw0,
                              const float* __restrict__ w_fw1, const float* __restrict__ w_bw1,
                              bf16* __restrict__ whTb)
{
    __shared__ float tile[32][33];
    int wl = blockIdx.z;
    const float* W; int D;
    if (wl == 0)      { W = w_fw0; D = EMB; }
    else if (wl == 1) { W = w_bw0; D = EMB; }
    else if (wl == 2) { W = w_fw1; D = TWOH; }
    else              { W = w_bw1; D = TWOH; }
    int k0 = blockIdx.x * 32, n0 = blockIdx.y * 32;
    int tx = threadIdx.x, ty = threadIdx.y;
    tile[ty][tx] = W[(size_t)(D + k0 + ty) * G4H + n0 + tx];
    __syncthreads();
    int k = k0 + tx;
    int n = n0 + ty;                  // gate-major column index
    int u = n & 511, g = n >> 9;
    whTb[(((size_t)wl * 512 + u) * 4 + g) * 512 + k] = __float2bfloat16(tile[tx][ty]);
}

// -------- input-gate precompute GEMM: Gt[z][t][n][b] = (gather(A) @ Wx + bias)^T --------
__global__ __launch_bounds__(256)
void gates_gemm(const bf16* __restrict__ A, int strideA, int Keff,
                const float* __restrict__ W_fw, const float* __restrict__ W_bw,
                const float* __restrict__ b_fw, const float* __restrict__ b_bw,
                const int* __restrict__ lengths,
                bf16* __restrict__ Gt)
{
    const int z = blockIdx.z;
    const float* W    = z ? W_bw : W_fw;
    const float* bias = z ? b_bw : b_fw;
    const int m0 = blockIdx.x * 128;
    const int n0 = blockIdx.y * 128;
    const int tid = threadIdx.x;

    __shared__ __align__(16) float As[16][132];
    __shared__ __align__(16) float Bs[16][132];

    const int row_l = tid >> 1;
    const int kseg  = (tid & 1) * 8;
    int r = m0 + row_l;
    int t = r >> 6, b = r & 63;
    int st = t;
    if (z) { int len = lengths[b]; st = (t < len) ? (len - 1 - t) : t; }
    const bf16* arow = A + (size_t)(st * BATCH + b) * strideA + kseg;

    const int krow = tid >> 4;
    const int nseg = (tid & 15) * 8;
    const float* brow = W + (size_t)krow * G4H + n0 + nseg;

    const int ty = tid >> 4, tx = tid & 15;
    const int mt = ty * 8, nt = tx * 8;

    float acc[8][8];
#pragma unroll
    for (int i = 0; i < 8; ++i)
#pragma unroll
        for (int j = 0; j < 8; ++j) acc[i][j] = 0.f;

    for (int kt = 0; kt < Keff; kt += 16) {
        uint4 av = *reinterpret_cast<const uint4*>(arow + kt);
        const unsigned short* as8 = reinterpret_cast<const unsigned short*>(&av);
        float4 bld0 = *reinterpret_cast<const float4*>(brow + (size_t)kt * G4H);
        float4 bld1 = *reinterpret_cast<const float4*>(brow + (size_t)kt * G4H + 4);
#pragma unroll
        for (int j = 0; j < 8; ++j) As[kseg + j][row_l] = us2f(as8[j]);
        *reinterpret_cast<float4*>(&Bs[krow][nseg])     = bld0;
        *reinterpret_cast<float4*>(&Bs[krow][nseg + 4]) = bld1;
        __syncthreads();
#pragma unroll
        for (int k = 0; k < 16; ++k) {
            float4 a0 = *reinterpret_cast<const float4*>(&As[k][mt]);
            float4 a1 = *reinterpret_cast<const float4*>(&As[k][mt + 4]);
            float4 c0 = *reinterpret_cast<const float4*>(&Bs[k][nt]);
            float4 c1 = *reinterpret_cast<const float4*>(&Bs[k][nt + 4]);
            float a8[8] = {a0.x,a0.y,a0.z,a0.w,a1.x,a1.y,a1.z,a1.w};
            float b8[8] = {c0.x,c0.y,c0.z,c0.w,c1.x,c1.y,c1.z,c1.w};
#pragma unroll
            for (int i = 0; i < 8; ++i)
#pragma unroll
                for (int j = 0; j < 8; ++j)
                    acc[i][j] = fmaf(a8[i], b8[j], acc[i][j]);
        }
        __syncthreads();
    }

    // epilogue: Gt[z][t][n][b] — i spans 8 consecutive b within one t (mt multiple of 8)
    const int t_ = (m0 + mt) >> 6;
    const int b0 = (m0 + mt) & 63;
#pragma unroll
    for (int j = 0; j < 8; ++j) {
        float bvj = bias[n0 + nt + j];
        __align__(16) bf16 tmp[8];
#pragma unroll
        for (int i = 0; i < 8; ++i) tmp[i] = __float2bfloat16(acc[i][j] + bvj);
        bf16* gout = Gt + (((size_t)z * S_LEN + t_) * G4H + (n0 + nt + j)) * BATCH + b0;
        *reinterpret_cast<uint4*>(gout) = *reinterpret_cast<const uint4*>(tmp);
    }
}

// ---------------- persistent MFMA LSTM recurrence (one layer, both dirs) ----------------
// 32 blocks = 2 dirs x 16 u-tiles (32 units x 4 gates = 128 gate-cols each). 4 waves/block;
// wave w owns units u0+w*8..+7, cols ordered [g][8u] -> 2 N-tiles. Weights live in 128
// persistent VGPRs as MFMA B-frags (zero per-step weight traffic). h (bf16, 64KB) staged
// LDS per step via agent atomics. Gates merged with one shfl_xor(8). R6 flag barrier.
__global__ __launch_bounds__(256, 1)
void lstm_seq(const bf16* __restrict__ Gt, const bf16* __restrict__ whTb,
              const int* __restrict__ lengths, unsigned short* __restrict__ hbuf,
              unsigned int* __restrict__ flags, bf16* __restrict__ hcat)
{
    __shared__ __align__(16) unsigned short hl[64 * 520];   // h tile, row pitch 520 bf16

    const int bx = blockIdx.x;       // 0..31
    const int d  = bx >> 4;
    const int nb = bx & 15;
    const int u0 = nb * 32;
    const int tid = threadIdx.x;
    const int w    = tid >> 6;
    const int l    = tid & 63;
    const int lo16 = l & 15;
    const int hi4  = l >> 4;
    const int du   = l & 7;
    const int g0   = (l >> 3) & 1;   // gate pair selector: 0 -> {i,f}, 1 -> {j,o}
    const int u    = u0 + w * 8 + du;
    const bool owner = (g0 == 0);

    // ---- persistent B fragments: B[k][c], lane holds col c=(c32 of N-tile), k=hi4*8+j ----
    bf8v bfr[2][16];
#pragma unroll
    for (int nt = 0; nt < 2; ++nt) {
        const bf16* wrow = whTb + (((size_t)d * 512 + u) * 4 + (nt * 2 + g0)) * 512 + hi4 * 8;
#pragma unroll
        for (int kt = 0; kt < 16; ++kt)
            bfr[nt][kt] = *reinterpret_cast<const bf8v*>(wrow + kt * 32);
    }

    int   len_st[16];
    float c_st[16], h_st[16];
#pragma unroll
    for (int mt = 0; mt < 4; ++mt)
#pragma unroll
        for (int rr = 0; rr < 4; ++rr) {
            len_st[mt * 4 + rr] = lengths[mt * 16 + hi4 * 4 + rr];
            c_st[mt * 4 + rr] = 0.f; h_st[mt * 4 + rr] = 0.f;
        }

    for (int t = 0; t < S_LEN; ++t) {
        // ---- stage h (64x512 bf16) into LDS via agent-coherent 8B loads ----
        const ull* hsrc = reinterpret_cast<const ull*>(
            hbuf + (size_t)((t & 1) * 2 + d) * BATCH * HID);
        ull pv[32];
#pragma unroll
        for (int i = 0; i < 32; ++i)
            pv[i] = __hip_atomic_load(hsrc + i * 256 + tid,
                                      __ATOMIC_RELAXED, __HIP_MEMORY_SCOPE_AGENT);

        // ---- acc init from Gt[d][t][n][b] (8B = 4 consecutive b) ----
        f32x4 acc[2][4];
#pragma unroll
        for (int nt = 0; nt < 2; ++nt) {
            const bf16* gtp = Gt + (((size_t)(d * S_LEN + t)) * G4H
                                    + (size_t)(nt * 2 + g0) * 512 + u) * BATCH + hi4 * 4;
#pragma unroll
            for (int mt = 0; mt < 4; ++mt) {
                ull gv = *reinterpret_cast<const ull*>(gtp + mt * 16);
                const unsigned short* gs = reinterpret_cast<const unsigned short*>(&gv);
                f32x4 av;
#pragma unroll
                for (int rr = 0; rr < 4; ++rr) av[rr] = us2f(gs[rr]);
                acc[nt][mt] = av;
            }
        }

#pragma unroll
        for (int i = 0; i < 32; ++i) {
            int e = (i * 256 + tid) * 4;             // bf16 flat index
            *reinterpret_cast<ull*>(&hl[(e >> 9) * 520 + (e & 511)]) = pv[i];
        }
        __syncthreads();

        // ---- MFMA: 16 k-steps x (4 A-frags + 8 mfma) ----
#pragma unroll
        for (int kt = 0; kt < 16; ++kt) {
            bf8v a[4];
#pragma unroll
            for (int mt = 0; mt < 4; ++mt)
                a[mt] = *reinterpret_cast<const bf8v*>(
                    &hl[(mt * 16 + lo16) * 520 + kt * 32 + hi4 * 8]);
#pragma unroll
            for (int nt = 0; nt < 2; ++nt)
#pragma unroll
                for (int mt = 0; mt < 4; ++mt)
                    acc[nt][mt] = __builtin_amdgcn_mfma_f32_16x16x32_bf16(
                        a[mt], bfr[nt][kt], acc[nt][mt], 0, 0, 0);
        }

        // ---- gate merge + pointwise (owner lanes: g0==0 hold i,f; partner l^8 holds j,o) ----
#pragma unroll
        for (int mt = 0; mt < 4; ++mt) {
            f32x4 vif0 = acc[0][mt], vif1 = acc[1][mt];
            float vj[4], vo[4];
#pragma unroll
            for (int rr = 0; rr < 4; ++rr) {
                vj[rr] = __shfl_xor(vif0[rr], 8, 64);
                vo[rr] = __shfl_xor(vif1[rr], 8, 64);
            }
            if (owner) {
#pragma unroll
                for (int rr = 0; rr < 4; ++rr) {
                    int idx = mt * 4 + rr;
                    bool msk = (t < len_st[idx]);
                    float i_ = sigm(vif0[rr]);
                    float j_ = tanhf(vj[rr]);
                    float f_ = sigm(vif1[rr] + 1.0f);   // FORGET_BIAS
                    float o_ = sigm(vo[rr]);
                    float cn = f_ * c_st[idx] + i_ * j_;
                    float hn = o_ * tanhf(cn);
                    if (msk) c_st[idx] = cn;
                    h_st[idx] = msk ? hn : h_st[idx];
                    int b = mt * 16 + hi4 * 4 + rr;
                    union { bf16 v; unsigned short s; } cv;
                    cv.v = __float2bfloat16(h_st[idx]);
                    __hip_atomic_store(hbuf + (size_t)(((t + 1) & 1) * 2 + d) * BATCH * HID
                                            + (size_t)b * HID + u,
                                       cv.s, __ATOMIC_RELAXED, __HIP_MEMORY_SCOPE_AGENT);
                }
            }
        }

        // ---- signal early ----
        asm volatile("s_waitcnt vmcnt(0)" ::: "memory");
        __syncthreads();
        if (tid == 0)
            __hip_atomic_store(&flags[(size_t)t * 32 + d * 16 + nb], 1u,
                               __ATOMIC_RELAXED, __HIP_MEMORY_SCOPE_AGENT);

        // ---- shadow: hcat stores ----
        if (owner) {
#pragma unroll
            for (int mt = 0; mt < 4; ++mt)
#pragma unroll
                for (int rr = 0; rr < 4; ++rr) {
                    int idx = mt * 4 + rr;
                    int b = mt * 16 + hi4 * 4 + rr;
                    bool msk = (t < len_st[idx]);
                    int p = (d == 1 && msk) ? (len_st[idx] - 1 - t) : t;
                    hcat[((size_t)p * BATCH + b) * TWOH + (size_t)d * HID + u] =
                        __float2bfloat16(msk ? h_st[idx] : 0.f);
                }
        }

        // ---- wait: poll this direction's 16 flags (read-only) ----
        if (tid < 16) {
            const unsigned int* fb = flags + (size_t)t * 32 + d * 16;
            while (__hip_atomic_load(fb + tid, __ATOMIC_RELAXED,
                                     __HIP_MEMORY_SCOPE_AGENT) == 0u)
                __builtin_amdgcn_s_sleep(2);
        }
        __syncthreads();
    }
}

// ---------------- dense + softmax: out[b][s][c] ----------------
__global__ __launch_bounds__(256)
void dense_softmax(const bf16* __restrict__ h, const float* __restrict__ wd,
                   const float* __restrict__ bd, float* __restrict__ out)
{
    __shared__ __align__(16) bf16 wdT[NCLS][1032];
    for (int i = threadIdx.x; i < TWOH * NCLS; i += 256) {
        int k = i / NCLS, c = i % NCLS;    // wd[k][c]
        wdT[c][k] = __float2bfloat16(wd[i]);
    }
    __syncthreads();
    const int c  = threadIdx.x & 31;
    const int rl = threadIdx.x >> 5;
#pragma unroll 1
    for (int pass = 0; pass < 8; ++pass) {
        int r = blockIdx.x * 64 + pass * 8 + rl;   // r = s*BATCH + b
        const bf16* hrow = h + (size_t)r * TWOH;
        float acc = -1e30f;
        if (c < NCLS) {
            acc = 0.f;
            for (int k = 0; k < TWOH; k += 8) {
                uint4 hv = *reinterpret_cast<const uint4*>(hrow + k);
                uint4 wv = *reinterpret_cast<const uint4*>(&wdT[c][k]);
                const unsigned short* hs  = reinterpret_cast<const unsigned short*>(&hv);
                const unsigned short* wsp = reinterpret_cast<const unsigned short*>(&wv);
#pragma unroll
                for (int j = 0; j < 8; ++j) acc += us2f(hs[j]) * us2f(wsp[j]);
            }
            acc += bd[c];
        }
        float mx = acc;
#pragma unroll
        for (int o = 16; o; o >>= 1) mx = fmaxf(mx, __shfl_xor(mx, o, 32));
        float e = (c < NCLS) ? __expf(acc - mx) : 0.f;
        float sm = e;
#pragma unroll
        for (int o = 16; o; o >>= 1) sm += __shfl_xor(sm, o, 32);
        if (c < NCLS) {
            int s = r >> 6, b = r & 63;
            out[((size_t)b * S_LEN + s) * NCLS + c] = e / sm;
        }
    }
}

extern "C" void kernel_launch(void* const* d_in, const int* in_sizes, int n_in,
                              void* d_out, int out_size, void* d_ws, size_t ws_size,
                              hipStream_t stream)
{
    const int*   ids   = (const int*)  d_in[0];
    const int*   lens  = (const int*)  d_in[1];
    const float* emb   = (const float*)d_in[2];
    const float* w_fw0 = (const float*)d_in[3];
    const float* b_fw0 = (const float*)d_in[4];
    const float* w_bw0 = (const float*)d_in[5];
    const float* b_bw0 = (const float*)d_in[6];
    const float* w_fw1 = (const float*)d_in[7];
    const float* b_fw1 = (const float*)d_in[8];
    const float* w_bw1 = (const float*)d_in[9];
    const float* b_bw1 = (const float*)d_in[10];
    const float* wd    = (const float*)d_in[11];
    const float* bd    = (const float*)d_in[12];
    float* out = (float*)d_out;

    char* ws = (char*)d_ws;
    size_t off = 0;
    auto alloc = [&](size_t bytes) {
        void* p = ws + off;
        off += (bytes + 255) & ~(size_t)255;
        return p;
    };
    bf16*  x      = (bf16*) alloc((size_t)S_LEN * BATCH * EPAD * 2);
    bf16*  Gt     = (bf16*) alloc((size_t)2 * S_LEN * G4H * BATCH * 2);
    bf16*  hcat0  = (bf16*) alloc((size_t)S_LEN * BATCH * TWOH * 2);
    bf16*  hcat1  = (bf16*) alloc((size_t)S_LEN * BATCH * TWOH * 2);
    bf16*  whTb   = (bf16*) alloc((size_t)4 * 512 * 4 * 512 * 2);
    unsigned short* hbuf = (unsigned short*)alloc((size_t)2 * 2 * BATCH * HID * 2);
    unsigned int* flags  = (unsigned int*) alloc((size_t)S_LEN * 32 * 4);

    embed_kernel<<<S_LEN * BATCH, 128, 0, stream>>>(ids, emb, x);
    wtrans_kernel<<<dim3(16, 64, 4), dim3(32, 32), 0, stream>>>(w_fw0, w_bw0, w_fw1, w_bw1, whTb);

    for (int layer = 0; layer < 2; ++layer) {
        hipMemsetAsync(hbuf, 0, (size_t)2 * 2 * BATCH * HID * 2, stream);
        hipMemsetAsync(flags, 0, (size_t)S_LEN * 32 * 4, stream);
        const bf16* Ain   = layer ? hcat0 : x;
        int strideA       = layer ? TWOH : EPAD;
        const float* Wf   = layer ? w_fw1 : w_fw0;
        const float* Wb   = layer ? w_bw1 : w_bw0;
        const float* bfp  = layer ? b_fw1 : b_fw0;
        const float* bbp  = layer ? b_bw1 : b_bw0;
        bf16* hcat        = layer ? hcat1 : hcat0;

        gates_gemm<<<dim3(128, 16, 2), 256, 0, stream>>>(Ain, strideA, strideA,
                                                         Wf, Wb, bfp, bbp, lens, Gt);

        const bf16*  Gp   = Gt;
        const bf16*  whp  = whTb + (size_t)layer * 2 * 512 * 4 * 512;
        const int*   lnp  = lens;
        unsigned short* hbp = hbuf;
        unsigned int* flp = flags;
        bf16*        hcp  = hcat;
        void* args[6] = { &Gp, &whp, &lnp, &hbp, &flp, &hcp };
        hipLaunchCooperativeKernel(lstm_seq, dim3(32), dim3(256), args, 0, stream);
    }
    dense_softmax<<<256, 256, 0, stream>>>(hcat1, wd, bd, out);

    (void)in_sizes; (void)n_in; (void)out_size; (void)ws_size;
}